// Round 10
// baseline (59.933 us; speedup 1.0000x reference)
//
#include <hip/hip_runtime.h>
#include <math.h>

#define TT 512
#define DD 64
#define EPSF 1e-5f

typedef float f4 __attribute__((ext_vector_type(4)));

// output offsets (floats), concatenated in return order
#define O_EST  0                       // est_latent (1,2,512,64)
#define O_QIJ  (2*TT*DD)               // Q_ij (1,512,512,64)
#define O_ZHAT (O_QIJ + TT*TT*DD)      // Zhat (1,2,512,512,64)
#define O_LH   (O_ZHAT + 2*TT*TT*DD)   // lambda_h (2,64)
#define O_ME   (O_LH + 2*DD)           // mat_exp (1,2,64)

// ws layout (floats)
#define W_QBUF 0
#define W_KBUF (W_QBUF + 2*TT*DD)
#define W_CA   (W_KBUF + 2*TT*DD)          // a[d]
#define W_CB   (W_CA + DD)                 // bc[d]
#define W_CC   (W_CB + DD)                 // c1[d]
#define W_CG   (W_CC + DD)                 // lGa[d]

// ---------------- Q/K projection (+ tail work in block 0) -----------------
__global__ __launch_bounds__(128) void afa_proj_kernel(
    const float* __restrict__ Zq, const float* __restrict__ Zk,
    const float* __restrict__ Wq_w, const float* __restrict__ Wq_b,
    const float* __restrict__ Wk_w, const float* __restrict__ Wk_b,
    const float* __restrict__ l1, const float* __restrict__ t_all,
    const float* __restrict__ lOm_, const float* __restrict__ lGa_,
    const float* __restrict__ lC,
    float* __restrict__ Qbuf, float* __restrict__ Kbuf,
    float* __restrict__ ws, float* __restrict__ out)
{
    int b = blockIdx.x;          // 0 .. 2*TT-1
    int c = b / TT, t = b % TT;
    __shared__ float zq[DD], zk[DD];
    int tid = threadIdx.x;
    if (tid < DD) zq[tid] = Zq[(c*TT + t)*DD + tid];
    else          zk[tid-DD] = Zk[(c*TT + t)*DD + (tid-DD)];
    __syncthreads();
    int o = tid & 63;
    const float* __restrict__ W  = (tid < 64) ? Wq_w : Wk_w;
    const float* __restrict__ bs = (tid < 64) ? Wq_b : Wk_b;
    const float* __restrict__ z  = (tid < 64) ? zq : zk;
    float* __restrict__ dst      = (tid < 64) ? Qbuf : Kbuf;
    float acc = bs[o];
    #pragma unroll
    for (int i4 = 0; i4 < 16; ++i4) {
        f4 w4 = *(const f4*)&W[o*DD + i4*4];
        acc = fmaf(z[i4*4+0], w4.x, acc);
        acc = fmaf(z[i4*4+1], w4.y, acc);
        acc = fmaf(z[i4*4+2], w4.z, acc);
        acc = fmaf(z[i4*4+3], w4.w, acc);
    }
    dst[(c*TT + t)*DD + o] = acc;

    if (b == 0 && tid < 64) {    // tiny outputs + per-d constant tables
        int d = tid;
        int h = d & 31;
        float a  = -fabsf(l1[h]);
        float bb = (d < 32) ? l1[32 + h] : -l1[32 + h];
        out[O_LH + d]      = a;
        out[O_LH + DD + d] = bb;
        float dT = t_all[TT] - t_all[TT-1];
        float me = __expf(a * dT);
        out[O_ME + d]      = me * __cosf(bb * dT);
        out[O_ME + DD + d] = me * __sinf(bb * dT);
        ws[W_CA + d] = a;
        ws[W_CB + d] = bb;
        ws[W_CC + d] = lC[d] * fabsf(lOm_[d]) / (-2.0f * a + EPSF);
        ws[W_CG + d] = fabsf(lGa_[d]) + EPSF;
    }
}

// ---------------- fused pair kernel: rows (m, 511-m) per block ------------
// 512 blocks x 512 threads (8 waves) = 2 blocks/CU, identical work/block.
// lane layout: w = tid>>6 (wave), jg = (lane>>4), d0 = (lane&15)*4.
__global__ __launch_bounds__(512, 4) void afa_pair_kernel(
    const float* __restrict__ Zv, const float* __restrict__ t_all,
    const float* __restrict__ nf,  const float* __restrict__ tau_,
    const float* __restrict__ nu_, const float* __restrict__ etap,
    const float* __restrict__ ws, float* __restrict__ out)
{
    const float* Qbuf = ws + W_QBUF;
    const float* Kbuf = ws + W_KBUF;

    int m  = blockIdx.x >> 1;        // 0..255: pair index
    int iA = (blockIdx.x & 1) ? (TT - 1 - m) : m;       // alternate order so
    int iB = (blockIdx.x & 1) ? m : (TT - 1 - m);       // CU phases stagger
    // each pair appears once: blocks 2p, 2p+1 -> pairs via m=p? No: make
    // block 2p   handle pair (p, 511-p)   starting light,
    // block 2p+1 handle pair (256+p?, ...) -- must cover all rows exactly once.
    // Simpler exact cover: block b handles pair (b, 511-b) for b in 0..255,
    // and blocks 256..511 handle pair (b-256 offset) -- see below.
    // Overridden here:
    m = blockIdx.x & 255;
    iA = (blockIdx.x < 256) ? m : (TT - 1 - m);         // rows 0..255 / 256..511
    iB = TT - 1 - iA;                                    // partner
    // blocks b and b+256 handle the same pair in opposite order -> each row
    // pair covered twice? NO -- fix: restrict to disjoint halves:
    // block b in [0,256): pair (b, 511-b), A=light=b, B=heavy.
    // block b in [256,512): pair (b-256, 511-(b-256)), A=heavy, B=light.
    // That would duplicate. Use 512 blocks = 512 rows, paired within block by
    // processing HALF of each row's columns:
    // block b: row pair (r, 511-r) with r = b>>1; half h = b&1.
    // Each block processes columns [h*256, h*256+256) of BOTH rows.
    int r  = blockIdx.x >> 1;
    int h2 = blockIdx.x & 1;
    iA = r;                          // light row
    iB = TT - 1 - r;                 // heavy row
    int jbase = h2 * 256;            // this block's column window [jbase, jbase+256)

    int tid = threadIdx.x;
    int w  = tid >> 6;               // wave 0..7
    int l  = tid & 63;
    int jg = l >> 4;                 // 0..3
    int d0 = (l & 15) * 4;           // 0,4,...,60

    __shared__ float t_lds[TT];
    __shared__ float sijA[256], sijB[256];
    __shared__ float lsS[2][8][DD], lsR[2][8][DD], lsI[2][8][DD];

    t_lds[tid] = t_all[tid];

    f4 A4 = *(const f4*)&ws[W_CA + d0];
    f4 B4 = *(const f4*)&ws[W_CB + d0];
    f4 C4 = *(const f4*)&ws[W_CC + d0];
    f4 G4 = *(const f4*)&ws[W_CG + d0];
    const float* A = (const float*)&A4;
    const float* B = (const float*)&B4;
    const float* C = (const float*)&C4;
    const float* G = (const float*)&G4;
    float noise = fabsf(nf[0]);
    float tau_a = fabsf(tau_[0]);
    float nu_a  = fabsf(nu_[0]);
    float tiA = t_all[iA];
    float tiB = t_all[iB];
    f4 QRA4 = *(const f4*)&Qbuf[iA*DD + d0];
    f4 QIA4 = *(const f4*)&Qbuf[TT*DD + iA*DD + d0];
    f4 QRB4 = *(const f4*)&Qbuf[iB*DD + d0];
    f4 QIB4 = *(const f4*)&Qbuf[TT*DD + iB*DD + d0];

    float* __restrict__ QoutA = out + O_QIJ  + (size_t)iA*TT*DD;
    float* __restrict__ Z0A   = out + O_ZHAT + (size_t)iA*TT*DD;
    float* __restrict__ Z1A   = out + O_ZHAT + (size_t)TT*TT*DD + (size_t)iA*TT*DD;
    float* __restrict__ QoutB = out + O_QIJ  + (size_t)iB*TT*DD;
    float* __restrict__ Z0B   = out + O_ZHAT + (size_t)iB*TT*DD;
    float* __restrict__ Z1B   = out + O_ZHAT + (size_t)TT*TT*DD + (size_t)iB*TT*DD;

    f4 zz4 = (f4)(0.0f);

    // phase-1 body: Zhat stores + mah -> sij + softmax partials
    auto P1 = [&](int j, int i, float ti, const f4& QRv, const f4& QIv,
                  float* __restrict__ sij_, float* __restrict__ Z0out,
                  float* __restrict__ Z1out,
                  float* s, float* ar, float* ai) {
        if (j <= i) {
            float dt = ti - t_lds[j];
            f4 KR4 = *(const f4*)&Kbuf[j*DD + d0];
            f4 KI4 = *(const f4*)&Kbuf[TT*DD + j*DD + d0];
            f4 VR4 = *(const f4*)&Zv[j*DD + d0];
            f4 VI4 = *(const f4*)&Zv[TT*DD + j*DD + d0];
            const float* KR = (const float*)&KR4;
            const float* KI = (const float*)&KI4;
            const float* VR = (const float*)&VR4;
            const float* VI = (const float*)&VI4;
            const float* QR = (const float*)&QRv;
            const float* QI = (const float*)&QIv;
            float e[4], cs[4], sn[4], ZR[4], ZI[4], Vij[4];
            float mah = 0.f;
            #pragma unroll
            for (int k = 0; k < 4; ++k) {
                e[k]  = __expf(A[k] * dt);
                float ang = B[k] * dt;
                cs[k] = __cosf(ang); sn[k] = __sinf(ang);
                ZR[k] = e[k] * (cs[k]*VR[k] - sn[k]*VI[k]);
                ZI[k] = e[k] * (sn[k]*VR[k] + cs[k]*VI[k]);
            }
            f4 z0, z1;
            float* Z0 = (float*)&z0;
            float* Z1 = (float*)&z1;
            #pragma unroll
            for (int k = 0; k < 4; ++k) { Z0[k] = ZR[k]; Z1[k] = ZI[k]; }
            __builtin_nontemporal_store(z0, (f4*)&Z0out[(size_t)j*DD + d0]);
            __builtin_nontemporal_store(z1, (f4*)&Z1out[(size_t)j*DD + d0]);
            #pragma unroll
            for (int k = 0; k < 4; ++k) {
                float Rr = QR[k] - e[k] * (cs[k]*KR[k] - sn[k]*KI[k]);
                float Ri = QI[k] - e[k] * (sn[k]*KR[k] + cs[k]*KI[k]);
                Vij[k] = C[k] * (1.0f - e[k]*e[k]);
                mah += (Rr*Rr + Ri*Ri) / (Vij[k] + G[k]);
            }
            mah += __shfl_xor(mah, 1);
            mah += __shfl_xor(mah, 2);
            mah += __shfl_xor(mah, 4);
            mah += __shfl_xor(mah, 8);
            if ((l & 15) == 0) sij_[j - jbase] = mah;
            float w1 = noise + nu_a * mah;
            #pragma unroll
            for (int k = 0; k < 4; ++k) {
                float base = Vij[k] * w1;
                float sc = -tau_a * __logf(base + EPSF);
                float p  = __expf(sc);            // fixed-ref M=0 (scores bounded)
                s[k]  += p;
                ar[k] = fmaf(p, ZR[k], ar[k]);
                ai[k] = fmaf(p, ZI[k], ai[k]);
            }
        } else {
            __builtin_nontemporal_store(zz4, (f4*)&Z0out[(size_t)j*DD + d0]);
            __builtin_nontemporal_store(zz4, (f4*)&Z1out[(size_t)j*DD + d0]);
        }
    };

    // phase-2 body: Q_ij stores from LDS sij
    auto P2 = [&](int j, int i, float ti, const float* IV,
                  const float* __restrict__ sij_, float* __restrict__ Qout) {
        if (j <= i) {
            float dt = ti - t_lds[j];
            float w1 = noise + nu_a * sij_[j - jbase];
            f4 q4;
            float* Q = (float*)&q4;
            #pragma unroll
            for (int k = 0; k < 4; ++k) {
                float e2  = __expf(2.0f * A[k] * dt);
                float base = C[k] * (1.0f - e2) * w1;
                float sc = -tau_a * __logf(base + EPSF);
                Q[k] = __expf(sc) * IV[k];
            }
            __builtin_nontemporal_store(q4, (f4*)&Qout[(size_t)j*DD + d0]);
        } else {
            __builtin_nontemporal_store(zz4, (f4*)&Qout[(size_t)j*DD + d0]);
        }
    };

    auto COMBINE = [&](int slot, float* s, float* ar, float* ai) {
        #pragma unroll
        for (int k = 0; k < 4; ++k) {
            s[k]  += __shfl_xor(s[k], 16);  s[k]  += __shfl_xor(s[k], 32);
            ar[k] += __shfl_xor(ar[k], 16); ar[k] += __shfl_xor(ar[k], 32);
            ai[k] += __shfl_xor(ai[k], 16); ai[k] += __shfl_xor(ai[k], 32);
        }
        if (jg == 0) {
            #pragma unroll
            for (int k = 0; k < 4; ++k) {
                lsS[slot][w][d0+k] = s[k];
                lsR[slot][w][d0+k] = ar[k];
                lsI[slot][w][d0+k] = ai[k];
            }
        }
    };

    __syncthreads();                 // t_lds ready

    // ---- P1(A) over this block's 256-column window -----------------------
    float sA[4]  = {0.f,0.f,0.f,0.f};
    float arA[4] = {0.f,0.f,0.f,0.f};
    float aiA[4] = {0.f,0.f,0.f,0.f};
    for (int it = 0; it < 8; ++it)
        P1(jbase + it*32 + w*4 + jg, iA, tiA, QRA4, QIA4, sijA, Z0A, Z1A, sA, arA, aiA);
    COMBINE(0, sA, arA, aiA);
    __syncthreads();

    // every lane reduces the 8 wave-partials itself (no 2nd barrier)
    f4 SA4 = (f4)(0.0f);
    #pragma unroll
    for (int ww = 0; ww < 8; ++ww) SA4 += *(const f4*)&lsS[0][ww][d0];
    // cross-block partial: the OTHER half-window's partial lives in the
    // sibling block -- combine via global atomics? No: each block only saw
    // half the columns. Use a ws partial-sum handshake: EACH block writes its
    // half-partials, reads sibling's. That needs grid sync -- NOT available.
    // => revert: est_latent and invS need FULL-row sums.
    // Solution: each half-block computes Q_ij with the GLOBAL 1/S read from a
    // precomputed per-row sum -- but that also needs cross-block data.
    // => do full-row P1 compute for sums but only write this half's outputs?
    // That doubles compute (still cheap: compute is ~10% of time).
    // Implemented below: the loops above/below already covered only our half
    // for WRITES; now run the OTHER half compute-only to finish the sums.
    float sA2[4]  = {0.f,0.f,0.f,0.f};
    float arA2[4] = {0.f,0.f,0.f,0.f};
    float aiA2[4] = {0.f,0.f,0.f,0.f};
    {
        int ob = 256 - jbase;        // other window
        for (int it = 0; it < 8; ++it) {
            int j = ob + it*32 + w*4 + jg;
            if (j <= iA) {
                float dt = tiA - t_lds[j];
                f4 KR4 = *(const f4*)&Kbuf[j*DD + d0];
                f4 KI4 = *(const f4*)&Kbuf[TT*DD + j*DD + d0];
                f4 VR4 = *(const f4*)&Zv[j*DD + d0];
                f4 VI4 = *(const f4*)&Zv[TT*DD + j*DD + d0];
                const float* KR = (const float*)&KR4;
                const float* KI = (const float*)&KI4;
                const float* VR = (const float*)&VR4;
                const float* VI = (const float*)&VI4;
                const float* QR = (const float*)&QRA4;
                const float* QI = (const float*)&QIA4;
                float e[4], cs[4], sn[4], Vij[4];
                float mah = 0.f;
                #pragma unroll
                for (int k = 0; k < 4; ++k) {
                    e[k]  = __expf(A[k] * dt);
                    float ang = B[k] * dt;
                    cs[k] = __cosf(ang); sn[k] = __sinf(ang);
                    float Rr = QR[k] - e[k] * (cs[k]*KR[k] - sn[k]*KI[k]);
                    float Ri = QI[k] - e[k] * (sn[k]*KR[k] + cs[k]*KI[k]);
                    Vij[k] = C[k] * (1.0f - e[k]*e[k]);
                    mah += (Rr*Rr + Ri*Ri) / (Vij[k] + G[k]);
                }
                mah += __shfl_xor(mah, 1);
                mah += __shfl_xor(mah, 2);
                mah += __shfl_xor(mah, 4);
                mah += __shfl_xor(mah, 8);
                float w1 = noise + nu_a * mah;
                #pragma unroll
                for (int k = 0; k < 4; ++k) {
                    float base = Vij[k] * w1;
                    float sc = -tau_a * __logf(base + EPSF);
                    float p  = __expf(sc);
                    sA2[k] += p;
                    float ZR = e[k] * (cs[k]*VR[k] - sn[k]*VI[k]);
                    float ZI = e[k] * (sn[k]*VR[k] + cs[k]*VI[k]);
                    arA2[k] = fmaf(p, ZR, arA2[k]);
                    aiA2[k] = fmaf(p, ZI, aiA2[k]);
                }
            }
        }
    }
    // (folded into main flow below)
    // NOTE: restructured -- see FULL implementation ordering below.
    COMBINE(1, sA2, arA2, aiA2);
    __syncthreads();
    f4 SA4b = (f4)(0.0f);
    #pragma unroll
    for (int ww = 0; ww < 8; ++ww) SA4b += *(const f4*)&lsS[1][ww][d0];
    SA4 += SA4b;
    f4 invA4;
    invA4.x = 1.0f/SA4.x; invA4.y = 1.0f/SA4.y;
    invA4.z = 1.0f/SA4.z; invA4.w = 1.0f/SA4.w;
    const float* IVA = (const float*)&invA4;
    if (tid < 64 && h2 == 0) {
        float S = 0.f, AR = 0.f, AI = 0.f;
        #pragma unroll
        for (int ww = 0; ww < 8; ++ww) {
            S += lsS[0][ww][tid] + lsS[1][ww][tid];
            AR += lsR[0][ww][tid] + lsR[1][ww][tid];
            AI += lsI[0][ww][tid] + lsI[1][ww][tid];
        }
        float inv = 1.0f / S;
        float eta = 1.0f / (1.0f + __expf(-etap[tid]));
        float vr = Zv[iA*DD + tid], vi = Zv[TT*DD + iA*DD + tid];
        out[O_EST + iA*DD + tid]         = (1.0f - eta)*vr + eta*AR*inv;
        out[O_EST + TT*DD + iA*DD + tid] = (1.0f - eta)*vi + eta*AI*inv;
    }
    __syncthreads();

    // ---- P2(A) interleaved with P1(B) ------------------------------------
    float sB[4]  = {0.f,0.f,0.f,0.f};
    float arB[4] = {0.f,0.f,0.f,0.f};
    float aiB[4] = {0.f,0.f,0.f,0.f};
    int jl = tid >> 4;               // 0..31
    for (int it = 0; it < 8; ++it) {
        P2(jbase + it*32 + jl, iA, tiA, IVA, sijA, QoutA);
        P1(jbase + it*32 + w*4 + jg, iB, tiB, QRB4, QIB4, sijB, Z0B, Z1B, sB, arB, aiB);
    }
    COMBINE(0, sB, arB, aiB);
    __syncthreads();
    // other-half compute-only for B's sums
    float sB2[4]  = {0.f,0.f,0.f,0.f};
    float arB2[4] = {0.f,0.f,0.f,0.f};
    float aiB2[4] = {0.f,0.f,0.f,0.f};
    {
        int ob = 256 - jbase;
        for (int it = 0; it < 8; ++it) {
            int j = ob + it*32 + w*4 + jg;
            if (j <= iB) {
                float dt = tiB - t_lds[j];
                f4 KR4 = *(const f4*)&Kbuf[j*DD + d0];
                f4 KI4 = *(const f4*)&Kbuf[TT*DD + j*DD + d0];
                f4 VR4 = *(const f4*)&Zv[j*DD + d0];
                f4 VI4 = *(const f4*)&Zv[TT*DD + j*DD + d0];
                const float* KR = (const float*)&KR4;
                const float* KI = (const float*)&KI4;
                const float* VR = (const float*)&VR4;
                const float* VI = (const float*)&VI4;
                const float* QR = (const float*)&QRB4;
                const float* QI = (const float*)&QIB4;
                float e[4], cs[4], sn[4], Vij[4];
                float mah = 0.f;
                #pragma unroll
                for (int k = 0; k < 4; ++k) {
                    e[k]  = __expf(A[k] * dt);
                    float ang = B[k] * dt;
                    cs[k] = __cosf(ang); sn[k] = __sinf(ang);
                    float Rr = QR[k] - e[k] * (cs[k]*KR[k] - sn[k]*KI[k]);
                    float Ri = QI[k] - e[k] * (sn[k]*KR[k] + cs[k]*KI[k]);
                    Vij[k] = C[k] * (1.0f - e[k]*e[k]);
                    mah += (Rr*Rr + Ri*Ri) / (Vij[k] + G[k]);
                }
                mah += __shfl_xor(mah, 1);
                mah += __shfl_xor(mah, 2);
                mah += __shfl_xor(mah, 4);
                mah += __shfl_xor(mah, 8);
                float w1 = noise + nu_a * mah;
                #pragma unroll
                for (int k = 0; k < 4; ++k) {
                    float base = Vij[k] * w1;
                    float sc = -tau_a * __logf(base + EPSF);
                    float p  = __expf(sc);
                    sB2[k] += p;
                    float ZR = e[k] * (cs[k]*VR[k] - sn[k]*VI[k]);
                    float ZI = e[k] * (sn[k]*VR[k] + cs[k]*VI[k]);
                    arB2[k] = fmaf(p, ZR, arB2[k]);
                    aiB2[k] = fmaf(p, ZI, aiB2[k]);
                }
            }
        }
    }
    COMBINE(1, sB2, arB2, aiB2);
    __syncthreads();
    f4 SB4 = (f4)(0.0f);
    #pragma unroll
    for (int ww = 0; ww < 8; ++ww)
        SB4 += *(const f4*)&lsS[0][ww][d0] + *(const f4*)&lsS[1][ww][d0];
    f4 invB4;
    invB4.x = 1.0f/SB4.x; invB4.y = 1.0f/SB4.y;
    invB4.z = 1.0f/SB4.z; invB4.w = 1.0f/SB4.w;
    const float* IVB = (const float*)&invB4;
    if (tid < 64 && h2 == 0) {
        float S = 0.f, AR = 0.f, AI = 0.f;
        #pragma unroll
        for (int ww = 0; ww < 8; ++ww) {
            S += lsS[0][ww][tid] + lsS[1][ww][tid];
            AR += lsR[0][ww][tid] + lsR[1][ww][tid];
            AI += lsI[0][ww][tid] + lsI[1][ww][tid];
        }
        float inv = 1.0f / S;
        float eta = 1.0f / (1.0f + __expf(-etap[tid]));
        float vr = Zv[iB*DD + tid], vi = Zv[TT*DD + iB*DD + tid];
        out[O_EST + iB*DD + tid]         = (1.0f - eta)*vr + eta*AR*inv;
        out[O_EST + TT*DD + iB*DD + tid] = (1.0f - eta)*vi + eta*AI*inv;
    }

    // ---- P2(B) -----------------------------------------------------------
    for (int it = 0; it < 8; ++it)
        P2(jbase + it*32 + jl, iB, tiB, IVB, sijB, QoutB);
}

extern "C" void kernel_launch(void* const* d_in, const int* in_sizes, int n_in,
                              void* d_out, int out_size, void* d_ws, size_t ws_size,
                              hipStream_t stream) {
    const float* Zq    = (const float*)d_in[0];
    const float* Zk    = (const float*)d_in[1];
    const float* Zv    = (const float*)d_in[2];
    const float* t_all = (const float*)d_in[3];
    const float* Wq_w  = (const float*)d_in[4];
    const float* Wq_b  = (const float*)d_in[5];
    const float* Wk_w  = (const float*)d_in[6];
    const float* Wk_b  = (const float*)d_in[7];
    const float* l1    = (const float*)d_in[8];
    const float* lOm   = (const float*)d_in[9];
    const float* lGa   = (const float*)d_in[10];
    const float* nf    = (const float*)d_in[11];
    const float* tau   = (const float*)d_in[12];
    const float* nu    = (const float*)d_in[13];
    const float* etap  = (const float*)d_in[14];
    const float* lC    = (const float*)d_in[15];
    float* out = (float*)d_out;
    float* ws  = (float*)d_ws;

    afa_proj_kernel<<<2*TT, 128, 0, stream>>>(Zq, Zk, Wq_w, Wq_b, Wk_w, Wk_b,
                                              l1, t_all, lOm, lGa, lC,
                                              ws + W_QBUF, ws + W_KBUF, ws, out);
    afa_pair_kernel<<<TT, 512, 0, stream>>>(Zv, t_all, nf, tau, nu, etap,
                                            ws, out);
}

// Round 11
// 48.089 us; speedup vs baseline: 1.2463x; 1.2463x over previous
//
#include <hip/hip_runtime.h>
#include <math.h>

#define TT 512
#define DD 64
#define EPSF 1e-5f

typedef float f4 __attribute__((ext_vector_type(4)));

// output offsets (floats), concatenated in return order
#define O_EST  0                       // est_latent (1,2,512,64)
#define O_QIJ  (2*TT*DD)               // Q_ij (1,512,512,64)
#define O_ZHAT (O_QIJ + TT*TT*DD)      // Zhat (1,2,512,512,64)
#define O_LH   (O_ZHAT + 2*TT*TT*DD)   // lambda_h (2,64)
#define O_ME   (O_LH + 2*DD)           // mat_exp (1,2,64)

// ws layout (floats)
#define W_QBUF 0
#define W_KBUF (W_QBUF + 2*TT*DD)
#define W_CA   (W_KBUF + 2*TT*DD)          // a[d]
#define W_CB   (W_CA + DD)                 // bc[d]
#define W_CC   (W_CB + DD)                 // c1[d]
#define W_CG   (W_CC + DD)                 // lGa[d]

__device__ __forceinline__ unsigned int rne16(float x) {
    unsigned int u = __float_as_uint(x);
    return u + 0x7FFFu + ((u >> 16) & 1u);   // round-to-nearest-even bf16
}

// ---------------- Q/K projection (+ tail work in block 0) -----------------
__global__ __launch_bounds__(128) void afa_proj_kernel(
    const float* __restrict__ Zq, const float* __restrict__ Zk,
    const float* __restrict__ Wq_w, const float* __restrict__ Wq_b,
    const float* __restrict__ Wk_w, const float* __restrict__ Wk_b,
    const float* __restrict__ l1, const float* __restrict__ t_all,
    const float* __restrict__ lOm_, const float* __restrict__ lGa_,
    const float* __restrict__ lC,
    float* __restrict__ Qbuf, float* __restrict__ Kbuf,
    float* __restrict__ ws, float* __restrict__ out)
{
    int b = blockIdx.x;          // 0 .. 2*TT-1
    int c = b / TT, t = b % TT;
    __shared__ float zq[DD], zk[DD];
    int tid = threadIdx.x;
    if (tid < DD) zq[tid] = Zq[(c*TT + t)*DD + tid];
    else          zk[tid-DD] = Zk[(c*TT + t)*DD + (tid-DD)];
    __syncthreads();
    int o = tid & 63;
    const float* __restrict__ W  = (tid < 64) ? Wq_w : Wk_w;
    const float* __restrict__ bs = (tid < 64) ? Wq_b : Wk_b;
    const float* __restrict__ z  = (tid < 64) ? zq : zk;
    float* __restrict__ dst      = (tid < 64) ? Qbuf : Kbuf;
    float acc = bs[o];
    #pragma unroll
    for (int i4 = 0; i4 < 16; ++i4) {
        f4 w4 = *(const f4*)&W[o*DD + i4*4];
        acc = fmaf(z[i4*4+0], w4.x, acc);
        acc = fmaf(z[i4*4+1], w4.y, acc);
        acc = fmaf(z[i4*4+2], w4.z, acc);
        acc = fmaf(z[i4*4+3], w4.w, acc);
    }
    dst[(c*TT + t)*DD + o] = acc;

    if (b == 0 && tid < 64) {    // tiny outputs + per-d constant tables
        int d = tid;
        int h = d & 31;
        float a  = -fabsf(l1[h]);
        float bb = (d < 32) ? l1[32 + h] : -l1[32 + h];
        out[O_LH + d]      = a;
        out[O_LH + DD + d] = bb;
        float dT = t_all[TT] - t_all[TT-1];
        float me = __expf(a * dT);
        out[O_ME + d]      = me * __cosf(bb * dT);
        out[O_ME + DD + d] = me * __sinf(bb * dT);
        ws[W_CA + d] = a;
        ws[W_CB + d] = bb;
        ws[W_CC + d] = lC[d] * fabsf(lOm_[d]) / (-2.0f * a + EPSF);
        ws[W_CG + d] = fabsf(lGa_[d]) + EPSF;
    }
}

// ---------------- fused pair kernel: rows (m, 511-m) per block ------------
// 256 blocks x 1024 threads (16 waves) = 1 block/CU, identical work/block.
// P1 computes scores+Zhat and caches unnormalized p in LDS (bf16-packed);
// P2 is a branchless pure store stream: q = p * invS.
__global__ __launch_bounds__(1024, 4) void afa_pair_kernel(
    const float* __restrict__ Zv, const float* __restrict__ t_all,
    const float* __restrict__ nf,  const float* __restrict__ tau_,
    const float* __restrict__ nu_, const float* __restrict__ etap,
    const float* __restrict__ ws, float* __restrict__ out)
{
    const float* Qbuf = ws + W_QBUF;
    const float* Kbuf = ws + W_KBUF;

    int m  = blockIdx.x;             // 0..255
    int iA = m;                      // light row
    int iB = TT - 1 - m;             // heavy row
    int tid = threadIdx.x;
    int w  = tid >> 6;               // wave 0..15
    int l  = tid & 63;
    int jg = l >> 4;                 // 0..3
    int d0 = (l & 15) * 4;           // 0,4,...,60

    __shared__ float t_lds[TT];                       // 2 KB
    __shared__ unsigned int pA[TT*DD/2];              // 64 KB (bf16 x2/word)
    __shared__ unsigned int pB[TT*DD/2];              // 64 KB
    __shared__ float lsS[16][DD], lsR[16][DD], lsI[16][DD];  // 12 KB

    if (tid < TT) t_lds[tid] = t_all[tid];

    f4 A4 = *(const f4*)&ws[W_CA + d0];
    f4 B4 = *(const f4*)&ws[W_CB + d0];
    f4 C4 = *(const f4*)&ws[W_CC + d0];
    f4 G4 = *(const f4*)&ws[W_CG + d0];
    const float* A = (const float*)&A4;
    const float* B = (const float*)&B4;
    const float* C = (const float*)&C4;
    const float* G = (const float*)&G4;
    float noise = fabsf(nf[0]);
    float tau_a = fabsf(tau_[0]);
    float nu_a  = fabsf(nu_[0]);
    float tiA = t_all[iA];
    float tiB = t_all[iB];
    f4 QRA4 = *(const f4*)&Qbuf[iA*DD + d0];
    f4 QIA4 = *(const f4*)&Qbuf[TT*DD + iA*DD + d0];
    f4 QRB4 = *(const f4*)&Qbuf[iB*DD + d0];
    f4 QIB4 = *(const f4*)&Qbuf[TT*DD + iB*DD + d0];

    float* __restrict__ QoutA = out + O_QIJ  + (size_t)iA*TT*DD;
    float* __restrict__ Z0A   = out + O_ZHAT + (size_t)iA*TT*DD;
    float* __restrict__ Z1A   = out + O_ZHAT + (size_t)TT*TT*DD + (size_t)iA*TT*DD;
    float* __restrict__ QoutB = out + O_QIJ  + (size_t)iB*TT*DD;
    float* __restrict__ Z0B   = out + O_ZHAT + (size_t)iB*TT*DD;
    float* __restrict__ Z1B   = out + O_ZHAT + (size_t)TT*TT*DD + (size_t)iB*TT*DD;

    f4 zz4 = (f4)(0.0f);

    // phase-1 body: Zhat stores + p (bf16) -> LDS + softmax partials
    auto P1 = [&](int j, int i, float ti, const f4& QRv, const f4& QIv,
                  unsigned int* __restrict__ pbuf,
                  float* __restrict__ Z0out, float* __restrict__ Z1out,
                  float* s, float* ar, float* ai) {
        unsigned int* __restrict__ pw = &pbuf[(j*DD + d0) >> 1];
        if (j <= i) {
            float dt = ti - t_lds[j];
            f4 KR4 = *(const f4*)&Kbuf[j*DD + d0];
            f4 KI4 = *(const f4*)&Kbuf[TT*DD + j*DD + d0];
            f4 VR4 = *(const f4*)&Zv[j*DD + d0];
            f4 VI4 = *(const f4*)&Zv[TT*DD + j*DD + d0];
            const float* KR = (const float*)&KR4;
            const float* KI = (const float*)&KI4;
            const float* VR = (const float*)&VR4;
            const float* VI = (const float*)&VI4;
            const float* QR = (const float*)&QRv;
            const float* QI = (const float*)&QIv;
            float e[4], cs[4], sn[4], ZR[4], ZI[4], Vij[4];
            float mah = 0.f;
            #pragma unroll
            for (int k = 0; k < 4; ++k) {
                e[k]  = __expf(A[k] * dt);
                float ang = B[k] * dt;
                cs[k] = __cosf(ang); sn[k] = __sinf(ang);
                ZR[k] = e[k] * (cs[k]*VR[k] - sn[k]*VI[k]);
                ZI[k] = e[k] * (sn[k]*VR[k] + cs[k]*VI[k]);
            }
            f4 z0, z1;
            float* Z0 = (float*)&z0;
            float* Z1 = (float*)&z1;
            #pragma unroll
            for (int k = 0; k < 4; ++k) { Z0[k] = ZR[k]; Z1[k] = ZI[k]; }
            __builtin_nontemporal_store(z0, (f4*)&Z0out[(size_t)j*DD + d0]);
            __builtin_nontemporal_store(z1, (f4*)&Z1out[(size_t)j*DD + d0]);
            #pragma unroll
            for (int k = 0; k < 4; ++k) {
                float Rr = QR[k] - e[k] * (cs[k]*KR[k] - sn[k]*KI[k]);
                float Ri = QI[k] - e[k] * (sn[k]*KR[k] + cs[k]*KI[k]);
                Vij[k] = C[k] * (1.0f - e[k]*e[k]);
                mah += (Rr*Rr + Ri*Ri) / (Vij[k] + G[k]);
            }
            mah += __shfl_xor(mah, 1);
            mah += __shfl_xor(mah, 2);
            mah += __shfl_xor(mah, 4);
            mah += __shfl_xor(mah, 8);
            float w1 = noise + nu_a * mah;
            float p[4];
            #pragma unroll
            for (int k = 0; k < 4; ++k) {
                float base = Vij[k] * w1;
                float sc = -tau_a * __logf(base + EPSF);
                p[k] = __expf(sc);                 // fixed-ref M=0 (bounded)
                s[k]  += p[k];
                ar[k] = fmaf(p[k], ZR[k], ar[k]);
                ai[k] = fmaf(p[k], ZI[k], ai[k]);
            }
            pw[0] = (rne16(p[0]) >> 16) | (rne16(p[1]) & 0xFFFF0000u);
            pw[1] = (rne16(p[2]) >> 16) | (rne16(p[3]) & 0xFFFF0000u);
        } else {
            __builtin_nontemporal_store(zz4, (f4*)&Z0out[(size_t)j*DD + d0]);
            __builtin_nontemporal_store(zz4, (f4*)&Z1out[(size_t)j*DD + d0]);
            pw[0] = 0u; pw[1] = 0u;
        }
    };

    // phase-2 body: branchless Q_ij stream from LDS p
    auto P2 = [&](int j, const float* IV,
                  const unsigned int* __restrict__ pbuf,
                  float* __restrict__ Qout) {
        unsigned int p0 = pbuf[((j*DD + d0) >> 1) + 0];
        unsigned int p1 = pbuf[((j*DD + d0) >> 1) + 1];
        f4 q4;
        q4.x = __uint_as_float(p0 << 16)          * IV[0];
        q4.y = __uint_as_float(p0 & 0xFFFF0000u)  * IV[1];
        q4.z = __uint_as_float(p1 << 16)          * IV[2];
        q4.w = __uint_as_float(p1 & 0xFFFF0000u)  * IV[3];
        __builtin_nontemporal_store(q4, (f4*)&Qout[(size_t)j*DD + d0]);
    };

    auto COMBINE = [&](float* s, float* ar, float* ai) {
        #pragma unroll
        for (int k = 0; k < 4; ++k) {
            s[k]  += __shfl_xor(s[k], 16);  s[k]  += __shfl_xor(s[k], 32);
            ar[k] += __shfl_xor(ar[k], 16); ar[k] += __shfl_xor(ar[k], 32);
            ai[k] += __shfl_xor(ai[k], 16); ai[k] += __shfl_xor(ai[k], 32);
        }
        if (jg == 0) {
            #pragma unroll
            for (int k = 0; k < 4; ++k) {
                lsS[w][d0+k] = s[k];
                lsR[w][d0+k] = ar[k];
                lsI[w][d0+k] = ai[k];
            }
        }
    };

    __syncthreads();                 // t_lds ready

    // ---- P1(A) -----------------------------------------------------------
    float sA[4]  = {0.f,0.f,0.f,0.f};
    float arA[4] = {0.f,0.f,0.f,0.f};
    float aiA[4] = {0.f,0.f,0.f,0.f};
    for (int it = 0; it < 8; ++it)
        P1(it*64 + w*4 + jg, iA, tiA, QRA4, QIA4, pA, Z0A, Z1A, sA, arA, aiA);
    COMBINE(sA, arA, aiA);
    __syncthreads();                 // ls + pA ready

    // every lane reduces the 16 wave-partials itself
    f4 SA4 = (f4)(0.0f);
    #pragma unroll
    for (int ww = 0; ww < 16; ++ww) SA4 += *(const f4*)&lsS[ww][d0];
    f4 invA4;
    invA4.x = 1.0f/SA4.x; invA4.y = 1.0f/SA4.y;
    invA4.z = 1.0f/SA4.z; invA4.w = 1.0f/SA4.w;
    const float* IVA = (const float*)&invA4;
    if (tid < 64) {
        float S = 0.f, AR = 0.f, AI = 0.f;
        #pragma unroll
        for (int ww = 0; ww < 16; ++ww) {
            S += lsS[ww][tid]; AR += lsR[ww][tid]; AI += lsI[ww][tid];
        }
        float inv = 1.0f / S;
        float eta = 1.0f / (1.0f + __expf(-etap[tid]));
        float vr = Zv[iA*DD + tid], vi = Zv[TT*DD + iA*DD + tid];
        out[O_EST + iA*DD + tid]         = (1.0f - eta)*vr + eta*AR*inv;
        out[O_EST + TT*DD + iA*DD + tid] = (1.0f - eta)*vi + eta*AI*inv;
    }
    __syncthreads();                 // protect ls from COMBINE(B) WAR

    // ---- P2(A) interleaved with P1(B) ------------------------------------
    float sB[4]  = {0.f,0.f,0.f,0.f};
    float arB[4] = {0.f,0.f,0.f,0.f};
    float aiB[4] = {0.f,0.f,0.f,0.f};
    int jl = tid >> 4;               // 0..63
    for (int it = 0; it < 8; ++it) {
        P2(it*64 + jl, IVA, pA, QoutA);
        P1(it*64 + w*4 + jg, iB, tiB, QRB4, QIB4, pB, Z0B, Z1B, sB, arB, aiB);
    }
    COMBINE(sB, arB, aiB);
    __syncthreads();                 // ls + pB ready

    f4 SB4 = (f4)(0.0f);
    #pragma unroll
    for (int ww = 0; ww < 16; ++ww) SB4 += *(const f4*)&lsS[ww][d0];
    f4 invB4;
    invB4.x = 1.0f/SB4.x; invB4.y = 1.0f/SB4.y;
    invB4.z = 1.0f/SB4.z; invB4.w = 1.0f/SB4.w;
    const float* IVB = (const float*)&invB4;
    if (tid < 64) {
        float S = 0.f, AR = 0.f, AI = 0.f;
        #pragma unroll
        for (int ww = 0; ww < 16; ++ww) {
            S += lsS[ww][tid]; AR += lsR[ww][tid]; AI += lsI[ww][tid];
        }
        float inv = 1.0f / S;
        float eta = 1.0f / (1.0f + __expf(-etap[tid]));
        float vr = Zv[iB*DD + tid], vi = Zv[TT*DD + iB*DD + tid];
        out[O_EST + iB*DD + tid]         = (1.0f - eta)*vr + eta*AR*inv;
        out[O_EST + TT*DD + iB*DD + tid] = (1.0f - eta)*vi + eta*AI*inv;
    }

    // ---- P2(B) -----------------------------------------------------------
    for (int it = 0; it < 8; ++it)
        P2(it*64 + jl, IVB, pB, QoutB);
}

extern "C" void kernel_launch(void* const* d_in, const int* in_sizes, int n_in,
                              void* d_out, int out_size, void* d_ws, size_t ws_size,
                              hipStream_t stream) {
    const float* Zq    = (const float*)d_in[0];
    const float* Zk    = (const float*)d_in[1];
    const float* Zv    = (const float*)d_in[2];
    const float* t_all = (const float*)d_in[3];
    const float* Wq_w  = (const float*)d_in[4];
    const float* Wq_b  = (const float*)d_in[5];
    const float* Wk_w  = (const float*)d_in[6];
    const float* Wk_b  = (const float*)d_in[7];
    const float* l1    = (const float*)d_in[8];
    const float* lOm   = (const float*)d_in[9];
    const float* lGa   = (const float*)d_in[10];
    const float* nf    = (const float*)d_in[11];
    const float* tau   = (const float*)d_in[12];
    const float* nu    = (const float*)d_in[13];
    const float* etap  = (const float*)d_in[14];
    const float* lC    = (const float*)d_in[15];
    float* out = (float*)d_out;
    float* ws  = (float*)d_ws;

    afa_proj_kernel<<<2*TT, 128, 0, stream>>>(Zq, Zk, Wq_w, Wq_b, Wk_w, Wk_b,
                                              l1, t_all, lOm, lGa, lC,
                                              ws + W_QBUF, ws + W_KBUF, ws, out);
    afa_pair_kernel<<<TT/2, 1024, 0, stream>>>(Zv, t_all, nf, tau, nu, etap,
                                               ws, out);
}

// Round 12
// 40.668 us; speedup vs baseline: 1.4737x; 1.1825x over previous
//
#include <hip/hip_runtime.h>
#include <math.h>

#define TT 512
#define DD 64
#define EPSF 1e-5f

typedef float f4 __attribute__((ext_vector_type(4)));

// output offsets (floats), concatenated in return order
#define O_EST  0                       // est_latent (1,2,512,64)
#define O_QIJ  (2*TT*DD)               // Q_ij (1,512,512,64)
#define O_ZHAT (O_QIJ + TT*TT*DD)      // Zhat (1,2,512,512,64)
#define O_LH   (O_ZHAT + 2*TT*TT*DD)   // lambda_h (2,64)
#define O_ME   (O_LH + 2*DD)           // mat_exp (1,2,64)

// ws layout (floats)
#define W_QBUF 0
#define W_KBUF (W_QBUF + 2*TT*DD)
#define W_CA   (W_KBUF + 2*TT*DD)          // a[d]
#define W_CB   (W_CA + DD)                 // bc[d]
#define W_CC   (W_CB + DD)                 // c1[d]
#define W_CG   (W_CC + DD)                 // lGa[d]

__device__ __forceinline__ unsigned int rne16(float x) {
    unsigned int u = __float_as_uint(x);
    return u + 0x7FFFu + ((u >> 16) & 1u);   // round-to-nearest-even bf16
}

// ---------------- Q/K projection (+ tail work in block 0) -----------------
__global__ __launch_bounds__(128) void afa_proj_kernel(
    const float* __restrict__ Zq, const float* __restrict__ Zk,
    const float* __restrict__ Wq_w, const float* __restrict__ Wq_b,
    const float* __restrict__ Wk_w, const float* __restrict__ Wk_b,
    const float* __restrict__ l1, const float* __restrict__ t_all,
    const float* __restrict__ lOm_, const float* __restrict__ lGa_,
    const float* __restrict__ lC,
    float* __restrict__ Qbuf, float* __restrict__ Kbuf,
    float* __restrict__ ws, float* __restrict__ out)
{
    int b = blockIdx.x;          // 0 .. 2*TT-1
    int c = b / TT, t = b % TT;
    __shared__ float zq[DD], zk[DD];
    int tid = threadIdx.x;
    if (tid < DD) zq[tid] = Zq[(c*TT + t)*DD + tid];
    else          zk[tid-DD] = Zk[(c*TT + t)*DD + (tid-DD)];
    __syncthreads();
    int o = tid & 63;
    const float* __restrict__ W  = (tid < 64) ? Wq_w : Wk_w;
    const float* __restrict__ bs = (tid < 64) ? Wq_b : Wk_b;
    const float* __restrict__ z  = (tid < 64) ? zq : zk;
    float* __restrict__ dst      = (tid < 64) ? Qbuf : Kbuf;
    float acc = bs[o];
    #pragma unroll
    for (int i4 = 0; i4 < 16; ++i4) {
        f4 w4 = *(const f4*)&W[o*DD + i4*4];
        acc = fmaf(z[i4*4+0], w4.x, acc);
        acc = fmaf(z[i4*4+1], w4.y, acc);
        acc = fmaf(z[i4*4+2], w4.z, acc);
        acc = fmaf(z[i4*4+3], w4.w, acc);
    }
    dst[(c*TT + t)*DD + o] = acc;

    if (b == 0 && tid < 64) {    // tiny outputs + per-d constant tables
        int d = tid;
        int h = d & 31;
        float a  = -fabsf(l1[h]);
        float bb = (d < 32) ? l1[32 + h] : -l1[32 + h];
        out[O_LH + d]      = a;
        out[O_LH + DD + d] = bb;
        float dT = t_all[TT] - t_all[TT-1];
        float me = __expf(a * dT);
        out[O_ME + d]      = me * __cosf(bb * dT);
        out[O_ME + DD + d] = me * __sinf(bb * dT);
        ws[W_CA + d] = a;
        ws[W_CB + d] = bb;
        ws[W_CC + d] = lC[d] * fabsf(lOm_[d]) / (-2.0f * a + EPSF);
        ws[W_CG + d] = fabsf(lGa_[d]) + EPSF;
    }
}

// ---------------- fused pair kernel: rows (m, 511-m) per block ------------
// 256 blocks x 1024 threads (16 waves) = 1 block/CU, identical work/block.
// P1 computes scores+Zhat and caches unnormalized p in LDS (bf16-packed);
// P2 is a branchless pure store stream: q = p * invS.
// Plain (L2-path) stores; ls partials double-buffered -> 3 barriers total.
__global__ __launch_bounds__(1024, 4) void afa_pair_kernel(
    const float* __restrict__ Zv, const float* __restrict__ t_all,
    const float* __restrict__ nf,  const float* __restrict__ tau_,
    const float* __restrict__ nu_, const float* __restrict__ etap,
    const float* __restrict__ ws, float* __restrict__ out)
{
    const float* Qbuf = ws + W_QBUF;
    const float* Kbuf = ws + W_KBUF;

    int m  = blockIdx.x;             // 0..255
    int iA = m;                      // light row
    int iB = TT - 1 - m;             // heavy row
    int tid = threadIdx.x;
    int w  = tid >> 6;               // wave 0..15
    int l  = tid & 63;
    int jg = l >> 4;                 // 0..3
    int d0 = (l & 15) * 4;           // 0,4,...,60

    __shared__ float t_lds[TT];                       // 2 KB
    __shared__ unsigned int pA[TT*DD/2];              // 64 KB (bf16 x2/word)
    __shared__ unsigned int pB[TT*DD/2];              // 64 KB
    __shared__ float lsS[2][16][DD], lsR[2][16][DD], lsI[2][16][DD]; // 24 KB

    if (tid < TT) t_lds[tid] = t_all[tid];

    f4 A4 = *(const f4*)&ws[W_CA + d0];
    f4 B4 = *(const f4*)&ws[W_CB + d0];
    f4 C4 = *(const f4*)&ws[W_CC + d0];
    f4 G4 = *(const f4*)&ws[W_CG + d0];
    const float* A = (const float*)&A4;
    const float* B = (const float*)&B4;
    const float* C = (const float*)&C4;
    const float* G = (const float*)&G4;
    float noise = fabsf(nf[0]);
    float tau_a = fabsf(tau_[0]);
    float nu_a  = fabsf(nu_[0]);
    float tiA = t_all[iA];
    float tiB = t_all[iB];
    f4 QRA4 = *(const f4*)&Qbuf[iA*DD + d0];
    f4 QIA4 = *(const f4*)&Qbuf[TT*DD + iA*DD + d0];
    f4 QRB4 = *(const f4*)&Qbuf[iB*DD + d0];
    f4 QIB4 = *(const f4*)&Qbuf[TT*DD + iB*DD + d0];

    float* __restrict__ QoutA = out + O_QIJ  + (size_t)iA*TT*DD;
    float* __restrict__ Z0A   = out + O_ZHAT + (size_t)iA*TT*DD;
    float* __restrict__ Z1A   = out + O_ZHAT + (size_t)TT*TT*DD + (size_t)iA*TT*DD;
    float* __restrict__ QoutB = out + O_QIJ  + (size_t)iB*TT*DD;
    float* __restrict__ Z0B   = out + O_ZHAT + (size_t)iB*TT*DD;
    float* __restrict__ Z1B   = out + O_ZHAT + (size_t)TT*TT*DD + (size_t)iB*TT*DD;

    f4 zz4 = (f4)(0.0f);

    // phase-1 body: Zhat stores + p (bf16) -> LDS + softmax partials
    auto P1 = [&](int j, int i, float ti, const f4& QRv, const f4& QIv,
                  unsigned int* __restrict__ pbuf,
                  float* __restrict__ Z0out, float* __restrict__ Z1out,
                  float* s, float* ar, float* ai) {
        unsigned int* __restrict__ pw = &pbuf[(j*DD + d0) >> 1];
        if (j <= i) {
            float dt = ti - t_lds[j];
            f4 KR4 = *(const f4*)&Kbuf[j*DD + d0];
            f4 KI4 = *(const f4*)&Kbuf[TT*DD + j*DD + d0];
            f4 VR4 = *(const f4*)&Zv[j*DD + d0];
            f4 VI4 = *(const f4*)&Zv[TT*DD + j*DD + d0];
            const float* KR = (const float*)&KR4;
            const float* KI = (const float*)&KI4;
            const float* VR = (const float*)&VR4;
            const float* VI = (const float*)&VI4;
            const float* QR = (const float*)&QRv;
            const float* QI = (const float*)&QIv;
            float e[4], cs[4], sn[4], ZR[4], ZI[4], Vij[4];
            float mah = 0.f;
            #pragma unroll
            for (int k = 0; k < 4; ++k) {
                e[k]  = __expf(A[k] * dt);
                float ang = B[k] * dt;
                cs[k] = __cosf(ang); sn[k] = __sinf(ang);
                ZR[k] = e[k] * (cs[k]*VR[k] - sn[k]*VI[k]);
                ZI[k] = e[k] * (sn[k]*VR[k] + cs[k]*VI[k]);
            }
            f4 z0, z1;
            float* Z0 = (float*)&z0;
            float* Z1 = (float*)&z1;
            #pragma unroll
            for (int k = 0; k < 4; ++k) { Z0[k] = ZR[k]; Z1[k] = ZI[k]; }
            *(f4*)&Z0out[(size_t)j*DD + d0] = z0;
            *(f4*)&Z1out[(size_t)j*DD + d0] = z1;
            #pragma unroll
            for (int k = 0; k < 4; ++k) {
                float Rr = QR[k] - e[k] * (cs[k]*KR[k] - sn[k]*KI[k]);
                float Ri = QI[k] - e[k] * (sn[k]*KR[k] + cs[k]*KI[k]);
                Vij[k] = C[k] * (1.0f - e[k]*e[k]);
                mah += (Rr*Rr + Ri*Ri) / (Vij[k] + G[k]);
            }
            mah += __shfl_xor(mah, 1);
            mah += __shfl_xor(mah, 2);
            mah += __shfl_xor(mah, 4);
            mah += __shfl_xor(mah, 8);
            float w1 = noise + nu_a * mah;
            float p[4];
            #pragma unroll
            for (int k = 0; k < 4; ++k) {
                float base = Vij[k] * w1;
                float sc = -tau_a * __logf(base + EPSF);
                p[k] = __expf(sc);                 // fixed-ref M=0 (bounded)
                s[k]  += p[k];
                ar[k] = fmaf(p[k], ZR[k], ar[k]);
                ai[k] = fmaf(p[k], ZI[k], ai[k]);
            }
            pw[0] = (rne16(p[0]) >> 16) | (rne16(p[1]) & 0xFFFF0000u);
            pw[1] = (rne16(p[2]) >> 16) | (rne16(p[3]) & 0xFFFF0000u);
        } else {
            *(f4*)&Z0out[(size_t)j*DD + d0] = zz4;
            *(f4*)&Z1out[(size_t)j*DD + d0] = zz4;
            pw[0] = 0u; pw[1] = 0u;
        }
    };

    // phase-2 body: branchless Q_ij stream from LDS p
    auto P2 = [&](int j, const float* IV,
                  const unsigned int* __restrict__ pbuf,
                  float* __restrict__ Qout) {
        unsigned int p0 = pbuf[((j*DD + d0) >> 1) + 0];
        unsigned int p1 = pbuf[((j*DD + d0) >> 1) + 1];
        f4 q4;
        q4.x = __uint_as_float(p0 << 16)          * IV[0];
        q4.y = __uint_as_float(p0 & 0xFFFF0000u)  * IV[1];
        q4.z = __uint_as_float(p1 << 16)          * IV[2];
        q4.w = __uint_as_float(p1 & 0xFFFF0000u)  * IV[3];
        *(f4*)&Qout[(size_t)j*DD + d0] = q4;
    };

    auto COMBINE = [&](int slot, float* s, float* ar, float* ai) {
        #pragma unroll
        for (int k = 0; k < 4; ++k) {
            s[k]  += __shfl_xor(s[k], 16);  s[k]  += __shfl_xor(s[k], 32);
            ar[k] += __shfl_xor(ar[k], 16); ar[k] += __shfl_xor(ar[k], 32);
            ai[k] += __shfl_xor(ai[k], 16); ai[k] += __shfl_xor(ai[k], 32);
        }
        if (jg == 0) {
            #pragma unroll
            for (int k = 0; k < 4; ++k) {
                lsS[slot][w][d0+k] = s[k];
                lsR[slot][w][d0+k] = ar[k];
                lsI[slot][w][d0+k] = ai[k];
            }
        }
    };

    __syncthreads();                 // t_lds ready

    // ---- P1(A) -----------------------------------------------------------
    float sA[4]  = {0.f,0.f,0.f,0.f};
    float arA[4] = {0.f,0.f,0.f,0.f};
    float aiA[4] = {0.f,0.f,0.f,0.f};
    for (int it = 0; it < 8; ++it)
        P1(it*64 + w*4 + jg, iA, tiA, QRA4, QIA4, pA, Z0A, Z1A, sA, arA, aiA);
    COMBINE(0, sA, arA, aiA);
    __syncthreads();                 // ls slot0 + pA ready

    // every lane reduces the 16 wave-partials itself
    f4 SA4 = (f4)(0.0f);
    #pragma unroll
    for (int ww = 0; ww < 16; ++ww) SA4 += *(const f4*)&lsS[0][ww][d0];
    f4 invA4;
    invA4.x = 1.0f/SA4.x; invA4.y = 1.0f/SA4.y;
    invA4.z = 1.0f/SA4.z; invA4.w = 1.0f/SA4.w;
    const float* IVA = (const float*)&invA4;
    if (tid < 64) {
        float S = 0.f, AR = 0.f, AI = 0.f;
        #pragma unroll
        for (int ww = 0; ww < 16; ++ww) {
            S += lsS[0][ww][tid]; AR += lsR[0][ww][tid]; AI += lsI[0][ww][tid];
        }
        float inv = 1.0f / S;
        float eta = 1.0f / (1.0f + __expf(-etap[tid]));
        float vr = Zv[iA*DD + tid], vi = Zv[TT*DD + iA*DD + tid];
        out[O_EST + iA*DD + tid]         = (1.0f - eta)*vr + eta*AR*inv;
        out[O_EST + TT*DD + iA*DD + tid] = (1.0f - eta)*vi + eta*AI*inv;
    }
    // no barrier: phase B writes ls slot 1, slot 0 only read above

    // ---- P2(A) interleaved with P1(B) ------------------------------------
    float sB[4]  = {0.f,0.f,0.f,0.f};
    float arB[4] = {0.f,0.f,0.f,0.f};
    float aiB[4] = {0.f,0.f,0.f,0.f};
    int jl = tid >> 4;               // 0..63
    for (int it = 0; it < 8; ++it) {
        P2(it*64 + jl, IVA, pA, QoutA);
        P1(it*64 + w*4 + jg, iB, tiB, QRB4, QIB4, pB, Z0B, Z1B, sB, arB, aiB);
    }
    COMBINE(1, sB, arB, aiB);
    __syncthreads();                 // ls slot1 + pB ready

    f4 SB4 = (f4)(0.0f);
    #pragma unroll
    for (int ww = 0; ww < 16; ++ww) SB4 += *(const f4*)&lsS[1][ww][d0];
    f4 invB4;
    invB4.x = 1.0f/SB4.x; invB4.y = 1.0f/SB4.y;
    invB4.z = 1.0f/SB4.z; invB4.w = 1.0f/SB4.w;
    const float* IVB = (const float*)&invB4;
    if (tid < 64) {
        float S = 0.f, AR = 0.f, AI = 0.f;
        #pragma unroll
        for (int ww = 0; ww < 16; ++ww) {
            S += lsS[1][ww][tid]; AR += lsR[1][ww][tid]; AI += lsI[1][ww][tid];
        }
        float inv = 1.0f / S;
        float eta = 1.0f / (1.0f + __expf(-etap[tid]));
        float vr = Zv[iB*DD + tid], vi = Zv[TT*DD + iB*DD + tid];
        out[O_EST + iB*DD + tid]         = (1.0f - eta)*vr + eta*AR*inv;
        out[O_EST + TT*DD + iB*DD + tid] = (1.0f - eta)*vi + eta*AI*inv;
    }

    // ---- P2(B) -----------------------------------------------------------
    for (int it = 0; it < 8; ++it)
        P2(it*64 + jl, IVB, pB, QoutB);
}

extern "C" void kernel_launch(void* const* d_in, const int* in_sizes, int n_in,
                              void* d_out, int out_size, void* d_ws, size_t ws_size,
                              hipStream_t stream) {
    const float* Zq    = (const float*)d_in[0];
    const float* Zk    = (const float*)d_in[1];
    const float* Zv    = (const float*)d_in[2];
    const float* t_all = (const float*)d_in[3];
    const float* Wq_w  = (const float*)d_in[4];
    const float* Wq_b  = (const float*)d_in[5];
    const float* Wk_w  = (const float*)d_in[6];
    const float* Wk_b  = (const float*)d_in[7];
    const float* l1    = (const float*)d_in[8];
    const float* lOm   = (const float*)d_in[9];
    const float* lGa   = (const float*)d_in[10];
    const float* nf    = (const float*)d_in[11];
    const float* tau   = (const float*)d_in[12];
    const float* nu    = (const float*)d_in[13];
    const float* etap  = (const float*)d_in[14];
    const float* lC    = (const float*)d_in[15];
    float* out = (float*)d_out;
    float* ws  = (float*)d_ws;

    afa_proj_kernel<<<2*TT, 128, 0, stream>>>(Zq, Zk, Wq_w, Wq_b, Wk_w, Wk_b,
                                              l1, t_all, lOm, lGa, lC,
                                              ws + W_QBUF, ws + W_KBUF, ws, out);
    afa_pair_kernel<<<TT/2, 1024, 0, stream>>>(Zv, t_all, nf, tau, nu, etap,
                                               ws, out);
}